// Round 4
// baseline (337.696 us; speedup 1.0000x reference)
//
#include <hip/hip_runtime.h>

#define NN 50000
#define NE 800000
#define NB 782    // ceil(NN/64) buckets of 64 dst-nodes
#define CAP 1536  // per-bucket edge capacity (avg 1023, sigma 32 -> +16 sigma)

// ---------------- bf16 helpers (bits-level, RNE) ----------------

__device__ __forceinline__ unsigned short f2bf(float f) {
    union { float f; unsigned u; } v; v.f = f;
    unsigned u = v.u;
    return (unsigned short)((u + 0x7fffu + ((u >> 16) & 1u)) >> 16);
}
__device__ __forceinline__ float bfu_lo(unsigned p) {  // low bf16 of packed pair
    union { unsigned u; float f; } v; v.u = p << 16; return v.f;
}
__device__ __forceinline__ float bfu_hi(unsigned p) {  // high bf16 of packed pair
    union { unsigned u; float f; } v; v.u = p & 0xffff0000u; return v.f;
}

typedef __bf16 bf16x8 __attribute__((ext_vector_type(8)));
typedef float f32x4 __attribute__((ext_vector_type(4)));
union U16 { uint4 u; bf16x8 v; };

// async global->LDS, 16B per lane. LDS dest must be WAVE-UNIFORM base (+ lane*16 implicit);
// global src is per-lane. (guide m97/m104 semantics)
typedef unsigned int u32_as1 __attribute__((address_space(1)));
typedef unsigned int u32_as3 __attribute__((address_space(3)));
__device__ __forceinline__ void gload_lds16(const void* g, void* l) {
    __builtin_amdgcn_global_load_lds((const u32_as1*)g, (u32_as3*)l, 16, 0, 0);
}

// ---------------- CSR build: binned scatter (block-private contiguous write runs) ----------

__global__ __launch_bounds__(512) void binscatter_kernel(const int* __restrict__ src,
                                                         const int* __restrict__ dst,
                                                         int* __restrict__ bcnt,
                                                         unsigned* __restrict__ ebuf) {
    __shared__ int hist[NB];
    __shared__ int base[NB];
    const int BE = 8192;  // edges per block
    int tid = threadIdx.x;
    int e0 = blockIdx.x * BE;
    for (int i = tid; i < NB; i += 512) hist[i] = 0;
    __syncthreads();
    for (int i = tid; i < BE; i += 512) {
        int e = e0 + i;
        if (e < NE) atomicAdd(&hist[dst[e] >> 6], 1);
    }
    __syncthreads();
    for (int i = tid; i < NB; i += 512) {
        int c = hist[i];
        base[i] = c ? atomicAdd(&bcnt[i], c) : 0;  // reserve contiguous run in bucket region
        hist[i] = 0;                                // reuse as cursor
    }
    __syncthreads();
    for (int i = tid; i < BE; i += 512) {
        int e = e0 + i;
        if (e < NE) {
            int d = dst[e], b = d >> 6;
            int slot = base[b] + atomicAdd(&hist[b], 1);
            if (slot < CAP)  // statistically impossible overflow guard
                ebuf[(size_t)b * CAP + slot] = (unsigned)src[e] | ((unsigned)(d & 63) << 16);
        }
    }
}

// one block per bucket: own prefix over bcnt + LDS degree hist (64 nodes) -> rowptr + col
__global__ __launch_bounds__(256) void csr_kernel(const int* __restrict__ bcnt,
                                                  const unsigned* __restrict__ ebuf,
                                                  int* __restrict__ rowptr,
                                                  int* __restrict__ col) {
    __shared__ int red[256];
    __shared__ int deg[64];
    __shared__ int cur[64];
    __shared__ int cbase_s;
    int b = blockIdx.x, tid = threadIdx.x;
    // exclusive prefix of bucket counts: sum bcnt[0..b) (all L2-hit)
    int s = 0;
    for (int i = tid; i < b; i += 256) s += bcnt[i];
    red[tid] = s;
    if (tid < 64) deg[tid] = 0;
    __syncthreads();
    for (int off = 128; off; off >>= 1) {
        if (tid < off) red[tid] += red[tid + off];
        __syncthreads();
    }
    if (tid == 0) cbase_s = red[0];
    __syncthreads();
    int cnt = bcnt[b], cbase = cbase_s;
    if (cnt > CAP) cnt = CAP;  // defensive: never read past bucket window
    const unsigned* eb = ebuf + (size_t)b * CAP;
    for (int i = tid; i < cnt; i += 256) atomicAdd(&deg[(eb[i] >> 16) & 63], 1);
    __syncthreads();
    if (tid == 0) {
        int run = 0;
        for (int j = 0; j < 64; j++) { cur[j] = run; run += deg[j]; }
    }
    __syncthreads();
    int node = b * 64 + tid;
    if (tid < 64 && node < NN) rowptr[node] = cbase + cur[tid];
    if (b == NB - 1 && tid == 0) rowptr[NN] = NE;
    __syncthreads();  // rowptr reads of cur[] complete before cursor atomics
    for (int i = tid; i < cnt; i += 256) {
        unsigned e = eb[i];
        int pos = atomicAdd(&cur[(e >> 16) & 63], 1);
        col[cbase + pos] = (int)(e & 0xffffu);
    }
}

// ---------------- fused fp32->bf16 cast + W pack ----------------
// blocks [0, CAST_BLK): cast x (4 elems/thread). blocks [CAST_BLK, +48): pack W1/W2.

template <int N>
__device__ __forceinline__ void pack_one(const float* __restrict__ Wl,
                                         const float* __restrict__ Wr,
                                         unsigned short* __restrict__ Wp, int t) {
    int lane = t & 63, c = t >> 6;
    int ks = c & 7, nt = c >> 3;
    int n = nt * 16 + (lane & 15);
    int kq = ks * 32 + (lane >> 4) * 8;
    unsigned short tmp[8];
#pragma unroll
    for (int j = 0; j < 8; j++) {
        int k = kq + j;
        float w = (k < 128) ? Wl[(size_t)k * N + n] : Wr[(size_t)(k - 128) * N + n];
        tmp[j] = f2bf(w);
    }
    ((ushort4*)Wp)[(size_t)c * 128 + lane * 2 + 0] = make_ushort4(tmp[0], tmp[1], tmp[2], tmp[3]);
    ((ushort4*)Wp)[(size_t)c * 128 + lane * 2 + 1] = make_ushort4(tmp[4], tmp[5], tmp[6], tmp[7]);
}

#define CAST_BLK (NN * 128 / 4 / 256)  // 6250 blocks exactly

__global__ void castpack_kernel(const float* __restrict__ in, unsigned short* __restrict__ outp,
                                const float* __restrict__ W1l, const float* __restrict__ W1r,
                                unsigned short* __restrict__ W1p,
                                const float* __restrict__ W2l, const float* __restrict__ W2r,
                                unsigned short* __restrict__ W2p) {
    if (blockIdx.x < CAST_BLK) {
        int i = blockIdx.x * 256 + threadIdx.x;
        float4 f = ((const float4*)in)[i];
        ushort4 o;
        o.x = f2bf(f.x); o.y = f2bf(f.y); o.z = f2bf(f.z); o.w = f2bf(f.w);
        ((ushort4*)outp)[i] = o;
    } else {
        int t = (blockIdx.x - CAST_BLK) * 256 + threadIdx.x;
        if (t < 8 * 8 * 64) pack_one<128>(W1l, W1r, W1p, t);
        else if (t < 8 * 8 * 64 + 16 * 8 * 64) pack_one<256>(W2l, W2r, W2p, t - 8 * 8 * 64);
    }
}

// ---------------- pull-based mean aggregation, bf16, 8-deep gather pipeline ----------------
// one wave per node. Index loads hoisted: one coalesced col[beg+lane] preload covers deg<=64
// (P(deg>64|lambda=16) ~ 1e-20; tail loop below for safety). Per iteration the wave issues
// 8 independent 256B row gathers (2 x 4 lane-groups, 16B/lane). Cross-group combine via
// shfl_xor(16,32); lanes 0..15 write the 256B output row.

__global__ void aggregate_bf_kernel(const int* __restrict__ rowptr, const int* __restrict__ col,
                                    const uint4* __restrict__ feat4,  // [NN][16] 16B chunks
                                    uint4* __restrict__ out4) {
    int wid = (blockIdx.x * blockDim.x + threadIdx.x) >> 6;
    int lane = threadIdx.x & 63;
    if (wid >= NN) return;
    int beg = rowptr[wid], end = rowptr[wid + 1];
    int deg = end - beg;
    int g = lane >> 4, c16 = lane & 15;
    int nmain = deg < 64 ? deg : 64;
    int cidx = (lane < nmain) ? col[beg + lane] : 0;  // coalesced index preload
    float acc[8];
#pragma unroll
    for (int j = 0; j < 8; j++) acc[j] = 0.f;
    for (int i = 0; i < nmain; i += 8) {
        int e0 = i + g, e1 = i + 4 + g;         // e always <= 63 (i <= 56)
        int s0 = __shfl(cidx, e0);
        int s1 = __shfl(cidx, e1);
        uint4 v0 = make_uint4(0u, 0u, 0u, 0u);
        uint4 v1 = make_uint4(0u, 0u, 0u, 0u);
        if (e0 < nmain) v0 = feat4[(size_t)s0 * 16 + c16];
        if (e1 < nmain) v1 = feat4[(size_t)s1 * 16 + c16];
        acc[0] += bfu_lo(v0.x); acc[1] += bfu_hi(v0.x);
        acc[2] += bfu_lo(v0.y); acc[3] += bfu_hi(v0.y);
        acc[4] += bfu_lo(v0.z); acc[5] += bfu_hi(v0.z);
        acc[6] += bfu_lo(v0.w); acc[7] += bfu_hi(v0.w);
        acc[0] += bfu_lo(v1.x); acc[1] += bfu_hi(v1.x);
        acc[2] += bfu_lo(v1.y); acc[3] += bfu_hi(v1.y);
        acc[4] += bfu_lo(v1.z); acc[5] += bfu_hi(v1.z);
        acc[6] += bfu_lo(v1.w); acc[7] += bfu_hi(v1.w);
    }
    // tail for deg > 64 (astronomically rare; correctness guard)
    for (int i = 64; i < deg; i += 4) {
        int idx = beg + i + g;
        if (idx < end) {
            int s = col[idx];
            uint4 v = feat4[(size_t)s * 16 + c16];
            acc[0] += bfu_lo(v.x); acc[1] += bfu_hi(v.x);
            acc[2] += bfu_lo(v.y); acc[3] += bfu_hi(v.y);
            acc[4] += bfu_lo(v.z); acc[5] += bfu_hi(v.z);
            acc[6] += bfu_lo(v.w); acc[7] += bfu_hi(v.w);
        }
    }
#pragma unroll
    for (int j = 0; j < 8; j++) {
        acc[j] += __shfl_xor(acc[j], 16);
        acc[j] += __shfl_xor(acc[j], 32);
    }
    if (g == 0) {
        float inv = (deg > 0) ? 1.0f / (float)deg : 0.0f;
        uint4 o;
        o.x = (unsigned)f2bf(acc[0] * inv) | ((unsigned)f2bf(acc[1] * inv) << 16);
        o.y = (unsigned)f2bf(acc[2] * inv) | ((unsigned)f2bf(acc[3] * inv) << 16);
        o.z = (unsigned)f2bf(acc[4] * inv) | ((unsigned)f2bf(acc[5] * inv) << 16);
        o.w = (unsigned)f2bf(acc[6] * inv) | ((unsigned)f2bf(acc[7] * inv) << 16);
        out4[(size_t)wid * 16 + c16] = o;
    }
}

// ---------------- MFMA GEMM + fused epilogue (LDS-staged W, 2 row-tiles/wave) --------------
// C[M,N] = [A0|A1](bf16) @ Wp + bias; sigmoid + row-L2 (+ log_softmax if FINAL).
// R3 post-mortem: register double-buffering of W is rescheduled away by hipcc (VGPR=108
// proved buffers weren't kept live); W-loads re-serialize at ~260cy L2 latency each.
// Fix: stage W into LDS with global_load_lds (compiler can't reorder across barriers),
// feed MFMA from ds_read_b128 (compiler emits fine-grained lgkmcnt - m97 evidence).
// 64KB LDS buffer -> 2 blocks/CU for stage/compute cross-block overlap; N=256 runs two
// 64KB phases. Each wave owns 32 rows (two 16-row tiles): every 1KB W chunk feeds 2 MFMAs,
// halving LDS read traffic. Block = 4 waves x 32 rows = 128 rows; grid = 391.
// A-frags: row-major 16B loads (A[m=lane&15][k=quad*8+j]); K=256 resident in 64 VGPRs.
// C/D: row=quad*4+reg, col=lane&15 -> row reductions are shfl_xor width-16 within the quad.

template <int N, bool FINAL>
__global__ __launch_bounds__(256) void gemm_mfma_kernel(
    const unsigned short* __restrict__ A0, const unsigned short* __restrict__ A1,
    const unsigned short* __restrict__ Wp, const float* __restrict__ bias,
    void* __restrict__ outp, int M) {
    const int NT = N / 16;   // total col tiles
    const int NPH = NT / 8;  // 64KB stage phases (1 for N=128, 2 for N=256)
    __shared__ unsigned char sW[65536];
    int tid = threadIdx.x, wave = tid >> 6, lane = tid & 63;
    int quad = lane >> 4, col = lane & 15;
    int m_base = blockIdx.x * 128 + wave * 32;

    // stage phase 0: each wave copies 16KB (16 x 1KB wave-instructions, async)
    {
        const char* gs = (const char*)Wp + wave * 16384;
        char* ld = (char*)sW + wave * 16384;  // wave-uniform LDS base (+lane*16 implicit)
#pragma unroll
        for (int j = 0; j < 16; j++) gload_lds16(gs + j * 1024 + lane * 16, ld + j * 1024);
    }

    // A-frags for two 16-row tiles (ks 0..3 from A0, 4..7 from A1)
    bf16x8 a0[8], a1[8];
    {
        int r0 = m_base + col;      int r0c = r0 < M ? r0 : M - 1;
        int r1 = m_base + 16 + col; int r1c = r1 < M ? r1 : M - 1;
        const uint4* p00 = (const uint4*)(A0 + (size_t)r0c * 128 + quad * 8);
        const uint4* p01 = (const uint4*)(A1 + (size_t)r0c * 128 + quad * 8);
        const uint4* p10 = (const uint4*)(A0 + (size_t)r1c * 128 + quad * 8);
        const uint4* p11 = (const uint4*)(A1 + (size_t)r1c * 128 + quad * 8);
#pragma unroll
        for (int ks = 0; ks < 4; ks++) { U16 u; u.u = p00[ks * 4]; a0[ks] = u.v; }
#pragma unroll
        for (int ks = 0; ks < 4; ks++) { U16 u; u.u = p01[ks * 4]; a0[4 + ks] = u.v; }
#pragma unroll
        for (int ks = 0; ks < 4; ks++) { U16 u; u.u = p10[ks * 4]; a1[ks] = u.v; }
#pragma unroll
        for (int ks = 0; ks < 4; ks++) { U16 u; u.u = p11[ks * 4]; a1[4 + ks] = u.v; }
    }

    f32x4 acc[2][NT];
#pragma unroll
    for (int t = 0; t < 2; t++)
#pragma unroll
        for (int nt = 0; nt < NT; nt++) acc[t][nt] = (f32x4){0.f, 0.f, 0.f, 0.f};

#pragma unroll
    for (int p = 0; p < NPH; p++) {
        __syncthreads();  // barrier drains vmcnt -> staged buffer ready
#pragma unroll
        for (int ks = 0; ks < 8; ks++) {
#pragma unroll
            for (int nt = 0; nt < 8; nt++) {
                U16 u;
                u.u = *(const uint4*)(sW + (nt * 8 + ks) * 1024 + lane * 16);
                acc[0][p * 8 + nt] = __builtin_amdgcn_mfma_f32_16x16x32_bf16(
                    a0[ks], u.v, acc[0][p * 8 + nt], 0, 0, 0);
                acc[1][p * 8 + nt] = __builtin_amdgcn_mfma_f32_16x16x32_bf16(
                    a1[ks], u.v, acc[1][p * 8 + nt], 0, 0, 0);
            }
        }
        if (p + 1 < NPH) {
            __syncthreads();  // all waves done reading sW before overwrite
            const char* gs = (const char*)Wp + (p + 1) * 65536 + wave * 16384;
            char* ld = (char*)sW + wave * 16384;
#pragma unroll
            for (int j = 0; j < 16; j++) gload_lds16(gs + j * 1024 + lane * 16, ld + j * 1024);
        }
    }

    // epilogue per row-tile: bias + sigmoid + row L2-norm (+ log_softmax if FINAL)
#pragma unroll
    for (int t = 0; t < 2; t++) {
        float ssq[4] = {0.f, 0.f, 0.f, 0.f};
#pragma unroll
        for (int nt = 0; nt < NT; nt++) {
            float bv = bias[nt * 16 + col];
#pragma unroll
            for (int r = 0; r < 4; r++) {
                float z = acc[t][nt][r] + bv;
                float s = 1.0f / (1.0f + __expf(-z));
                acc[t][nt][r] = s;
                ssq[r] += s * s;
            }
        }
#pragma unroll
        for (int r = 0; r < 4; r++) {
#pragma unroll
            for (int off = 1; off < 16; off <<= 1) ssq[r] += __shfl_xor(ssq[r], off, 16);
            float sc = 1.0f / fmaxf(sqrtf(ssq[r]), 1e-12f);
#pragma unroll
            for (int nt = 0; nt < NT; nt++) acc[t][nt][r] *= sc;
        }

        if (FINAL) {  // log_softmax; values in (0,1] post sigmoid+L2norm -> exp-sum stable
                      // without max subtraction (validated R3: absmax unchanged).
#pragma unroll
            for (int r = 0; r < 4; r++) {
                float se = 0.f;
#pragma unroll
                for (int nt = 0; nt < NT; nt++) se += __expf(acc[t][nt][r]);
#pragma unroll
                for (int off = 1; off < 16; off <<= 1) se += __shfl_xor(se, off, 16);
                float lse = __logf(se);
#pragma unroll
                for (int nt = 0; nt < NT; nt++) acc[t][nt][r] -= lse;
            }
            float* op = (float*)outp;
#pragma unroll
            for (int r = 0; r < 4; r++) {
                int m = m_base + t * 16 + quad * 4 + r;
                if (m < M) {
#pragma unroll
                    for (int nt = 0; nt < NT; nt++)
                        op[(size_t)m * N + nt * 16 + col] = acc[t][nt][r];
                }
            }
        } else {  // bf16 out (feeds aggregation 2 + GEMM2 A-operand)
            unsigned short* op = (unsigned short*)outp;
#pragma unroll
            for (int r = 0; r < 4; r++) {
                int m = m_base + t * 16 + quad * 4 + r;
                if (m < M) {
#pragma unroll
                    for (int nt = 0; nt < NT; nt++)
                        op[(size_t)m * N + nt * 16 + col] = f2bf(acc[t][nt][r]);
                }
            }
        }
    }
}

// ---------------- launcher ----------------

extern "C" void kernel_launch(void* const* d_in, const int* in_sizes, int n_in,
                              void* d_out, int out_size, void* d_ws, size_t ws_size,
                              hipStream_t stream) {
    const float* x   = (const float*)d_in[0];
    const int*   ei  = (const int*)d_in[1];
    const float* W1l = (const float*)d_in[2];
    const float* W1r = (const float*)d_in[3];
    const float* b1  = (const float*)d_in[4];
    const float* W2l = (const float*)d_in[5];
    const float* W2r = (const float*)d_in[6];
    const float* b2  = (const float*)d_in[7];
    float* out = (float*)d_out;

    const int* src = ei;
    const int* dst = ei + NE;

    char* ws = (char*)d_ws;
    size_t off = 0;
    auto alloc = [&](size_t bytes) -> void* {
        void* p = ws + off;
        off += (bytes + 255) / 256 * 256;
        return p;
    };
    int* rowptr     = (int*)alloc((size_t)(NN + 1) * 4);
    int* col        = (int*)alloc((size_t)NE * 4);
    int* bcnt       = (int*)alloc((size_t)NB * 4);
    unsigned* ebuf  = (unsigned*)alloc((size_t)NB * CAP * 4);  // 4.8MB
    unsigned short* x_bf   = (unsigned short*)alloc((size_t)NN * 128 * 2);
    unsigned short* agg_bf = (unsigned short*)alloc((size_t)NN * 128 * 2);
    unsigned short* h1_bf  = (unsigned short*)alloc((size_t)NN * 128 * 2);
    unsigned short* W1p    = (unsigned short*)alloc((size_t)8 * 8 * 64 * 8 * 2);    // 64KB
    unsigned short* W2p    = (unsigned short*)alloc((size_t)16 * 8 * 64 * 8 * 2);   // 128KB

    // CSR build (graph identical for both layers — build once)
    hipMemsetAsync(bcnt, 0, (size_t)NB * 4, stream);
    binscatter_kernel<<<(NE + 8191) / 8192, 512, 0, stream>>>(src, dst, bcnt, ebuf);
    csr_kernel<<<NB, 256, 0, stream>>>(bcnt, ebuf, rowptr, col);

    // prep: cast x to bf16 + pack both weight sets (fused, one launch)
    castpack_kernel<<<CAST_BLK + 48, 256, 0, stream>>>(x, x_bf, W1l, W1r, W1p, W2l, W2r, W2p);

    // layer 1
    aggregate_bf_kernel<<<(NN + 3) / 4, 256, 0, stream>>>(rowptr, col, (const uint4*)x_bf,
                                                          (uint4*)agg_bf);
    gemm_mfma_kernel<128, false><<<(NN + 127) / 128, 256, 0, stream>>>(agg_bf, x_bf, W1p, b1,
                                                                       h1_bf, NN);
    // layer 2
    aggregate_bf_kernel<<<(NN + 3) / 4, 256, 0, stream>>>(rowptr, col, (const uint4*)h1_bf,
                                                          (uint4*)agg_bf);
    gemm_mfma_kernel<256, true><<<(NN + 127) / 128, 256, 0, stream>>>(agg_bf, h1_bf, W2p, b2,
                                                                      out, NN);
}

// Round 5
// 222.497 us; speedup vs baseline: 1.5178x; 1.5178x over previous
//
#include <hip/hip_runtime.h>

#define NN 50000
#define NE 800000
#define NB 782    // ceil(NN/64) buckets of 64 dst-nodes
#define CAP 1536  // per-bucket edge capacity (avg 1023, sigma 32 -> +16 sigma)

// ---------------- bf16 helpers (bits-level, RNE) ----------------

__device__ __forceinline__ unsigned short f2bf(float f) {
    union { float f; unsigned u; } v; v.f = f;
    unsigned u = v.u;
    return (unsigned short)((u + 0x7fffu + ((u >> 16) & 1u)) >> 16);
}
__device__ __forceinline__ float bfu_lo(unsigned p) {  // low bf16 of packed pair
    union { unsigned u; float f; } v; v.u = p << 16; return v.f;
}
__device__ __forceinline__ float bfu_hi(unsigned p) {  // high bf16 of packed pair
    union { unsigned u; float f; } v; v.u = p & 0xffff0000u; return v.f;
}

typedef __bf16 bf16x8 __attribute__((ext_vector_type(8)));
typedef float f32x4 __attribute__((ext_vector_type(4)));
union U16 { uint4 u; bf16x8 v; };

// async global->LDS, 16B per lane. LDS dest must be WAVE-UNIFORM base (+ lane*16 implicit);
// global src is per-lane. (guide m97/m104 semantics)
typedef unsigned int u32_as1 __attribute__((address_space(1)));
typedef unsigned int u32_as3 __attribute__((address_space(3)));
__device__ __forceinline__ void gload_lds16(const void* g, void* l) {
    __builtin_amdgcn_global_load_lds((const u32_as1*)g, (u32_as3*)l, 16, 0, 0);
}

// ---------------- CSR build: binned scatter (block-private contiguous write runs) ----------

__global__ __launch_bounds__(512) void binscatter_kernel(const int* __restrict__ src,
                                                         const int* __restrict__ dst,
                                                         int* __restrict__ bcnt,
                                                         unsigned* __restrict__ ebuf) {
    __shared__ int hist[NB];
    __shared__ int base[NB];
    const int BE = 8192;  // edges per block
    int tid = threadIdx.x;
    int e0 = blockIdx.x * BE;
    for (int i = tid; i < NB; i += 512) hist[i] = 0;
    __syncthreads();
    for (int i = tid; i < BE; i += 512) {
        int e = e0 + i;
        if (e < NE) atomicAdd(&hist[dst[e] >> 6], 1);
    }
    __syncthreads();
    for (int i = tid; i < NB; i += 512) {
        int c = hist[i];
        base[i] = c ? atomicAdd(&bcnt[i], c) : 0;  // reserve contiguous run in bucket region
        hist[i] = 0;                                // reuse as cursor
    }
    __syncthreads();
    for (int i = tid; i < BE; i += 512) {
        int e = e0 + i;
        if (e < NE) {
            int d = dst[e], b = d >> 6;
            int slot = base[b] + atomicAdd(&hist[b], 1);
            if (slot < CAP)  // statistically impossible overflow guard
                ebuf[(size_t)b * CAP + slot] = (unsigned)src[e] | ((unsigned)(d & 63) << 16);
        }
    }
}

// one block per bucket: own prefix over bcnt + LDS degree hist (64 nodes) -> rowptr + col
__global__ __launch_bounds__(256) void csr_kernel(const int* __restrict__ bcnt,
                                                  const unsigned* __restrict__ ebuf,
                                                  int* __restrict__ rowptr,
                                                  int* __restrict__ col) {
    __shared__ int red[256];
    __shared__ int deg[64];
    __shared__ int cur[64];
    __shared__ int cbase_s;
    int b = blockIdx.x, tid = threadIdx.x;
    // exclusive prefix of bucket counts: sum bcnt[0..b) (all L2-hit)
    int s = 0;
    for (int i = tid; i < b; i += 256) s += bcnt[i];
    red[tid] = s;
    if (tid < 64) deg[tid] = 0;
    __syncthreads();
    for (int off = 128; off; off >>= 1) {
        if (tid < off) red[tid] += red[tid + off];
        __syncthreads();
    }
    if (tid == 0) cbase_s = red[0];
    __syncthreads();
    int cnt = bcnt[b], cbase = cbase_s;
    if (cnt > CAP) cnt = CAP;  // defensive: never read past bucket window
    const unsigned* eb = ebuf + (size_t)b * CAP;
    for (int i = tid; i < cnt; i += 256) atomicAdd(&deg[(eb[i] >> 16) & 63], 1);
    __syncthreads();
    if (tid == 0) {
        int run = 0;
        for (int j = 0; j < 64; j++) { cur[j] = run; run += deg[j]; }
    }
    __syncthreads();
    int node = b * 64 + tid;
    if (tid < 64 && node < NN) rowptr[node] = cbase + cur[tid];
    if (b == NB - 1 && tid == 0) rowptr[NN] = NE;
    __syncthreads();  // rowptr reads of cur[] complete before cursor atomics
    for (int i = tid; i < cnt; i += 256) {
        unsigned e = eb[i];
        int pos = atomicAdd(&cur[(e >> 16) & 63], 1);
        col[cbase + pos] = (int)(e & 0xffffu);
    }
}

// ---------------- fused fp32->bf16 cast + W pack ----------------
// blocks [0, CAST_BLK): cast x (4 elems/thread). blocks [CAST_BLK, +48): pack W1/W2.

template <int N>
__device__ __forceinline__ void pack_one(const float* __restrict__ Wl,
                                         const float* __restrict__ Wr,
                                         unsigned short* __restrict__ Wp, int t) {
    int lane = t & 63, c = t >> 6;
    int ks = c & 7, nt = c >> 3;
    int n = nt * 16 + (lane & 15);
    int kq = ks * 32 + (lane >> 4) * 8;
    unsigned short tmp[8];
#pragma unroll
    for (int j = 0; j < 8; j++) {
        int k = kq + j;
        float w = (k < 128) ? Wl[(size_t)k * N + n] : Wr[(size_t)(k - 128) * N + n];
        tmp[j] = f2bf(w);
    }
    ((ushort4*)Wp)[(size_t)c * 128 + lane * 2 + 0] = make_ushort4(tmp[0], tmp[1], tmp[2], tmp[3]);
    ((ushort4*)Wp)[(size_t)c * 128 + lane * 2 + 1] = make_ushort4(tmp[4], tmp[5], tmp[6], tmp[7]);
}

#define CAST_BLK (NN * 128 / 4 / 256)  // 6250 blocks exactly

__global__ void castpack_kernel(const float* __restrict__ in, unsigned short* __restrict__ outp,
                                const float* __restrict__ W1l, const float* __restrict__ W1r,
                                unsigned short* __restrict__ W1p,
                                const float* __restrict__ W2l, const float* __restrict__ W2r,
                                unsigned short* __restrict__ W2p) {
    if (blockIdx.x < CAST_BLK) {
        int i = blockIdx.x * 256 + threadIdx.x;
        float4 f = ((const float4*)in)[i];
        ushort4 o;
        o.x = f2bf(f.x); o.y = f2bf(f.y); o.z = f2bf(f.z); o.w = f2bf(f.w);
        ((ushort4*)outp)[i] = o;
    } else {
        int t = (blockIdx.x - CAST_BLK) * 256 + threadIdx.x;
        if (t < 8 * 8 * 64) pack_one<128>(W1l, W1r, W1p, t);
        else if (t < 8 * 8 * 64 + 16 * 8 * 64) pack_one<256>(W2l, W2r, W2p, t - 8 * 8 * 64);
    }
}

// ---------------- pull-based mean aggregation, bf16, 8-deep gather pipeline ----------------
// one wave per node. Index loads hoisted: one coalesced col[beg+lane] preload covers deg<=64
// (P(deg>64|lambda=16) ~ 1e-20; tail loop below for safety). Per iteration the wave issues
// 8 independent 256B row gathers (2 x 4 lane-groups, 16B/lane). Cross-group combine via
// shfl_xor(16,32); lanes 0..15 write the 256B output row.

__global__ void aggregate_bf_kernel(const int* __restrict__ rowptr, const int* __restrict__ col,
                                    const uint4* __restrict__ feat4,  // [NN][16] 16B chunks
                                    uint4* __restrict__ out4) {
    int wid = (blockIdx.x * blockDim.x + threadIdx.x) >> 6;
    int lane = threadIdx.x & 63;
    if (wid >= NN) return;
    int beg = rowptr[wid], end = rowptr[wid + 1];
    int deg = end - beg;
    int g = lane >> 4, c16 = lane & 15;
    int nmain = deg < 64 ? deg : 64;
    int cidx = (lane < nmain) ? col[beg + lane] : 0;  // coalesced index preload
    float acc[8];
#pragma unroll
    for (int j = 0; j < 8; j++) acc[j] = 0.f;
    for (int i = 0; i < nmain; i += 8) {
        int e0 = i + g, e1 = i + 4 + g;         // e always <= 63 (i <= 56)
        int s0 = __shfl(cidx, e0);
        int s1 = __shfl(cidx, e1);
        uint4 v0 = make_uint4(0u, 0u, 0u, 0u);
        uint4 v1 = make_uint4(0u, 0u, 0u, 0u);
        if (e0 < nmain) v0 = feat4[(size_t)s0 * 16 + c16];
        if (e1 < nmain) v1 = feat4[(size_t)s1 * 16 + c16];
        acc[0] += bfu_lo(v0.x); acc[1] += bfu_hi(v0.x);
        acc[2] += bfu_lo(v0.y); acc[3] += bfu_hi(v0.y);
        acc[4] += bfu_lo(v0.z); acc[5] += bfu_hi(v0.z);
        acc[6] += bfu_lo(v0.w); acc[7] += bfu_hi(v0.w);
        acc[0] += bfu_lo(v1.x); acc[1] += bfu_hi(v1.x);
        acc[2] += bfu_lo(v1.y); acc[3] += bfu_hi(v1.y);
        acc[4] += bfu_lo(v1.z); acc[5] += bfu_hi(v1.z);
        acc[6] += bfu_lo(v1.w); acc[7] += bfu_hi(v1.w);
    }
    // tail for deg > 64 (astronomically rare; correctness guard)
    for (int i = 64; i < deg; i += 4) {
        int idx = beg + i + g;
        if (idx < end) {
            int s = col[idx];
            uint4 v = feat4[(size_t)s * 16 + c16];
            acc[0] += bfu_lo(v.x); acc[1] += bfu_hi(v.x);
            acc[2] += bfu_lo(v.y); acc[3] += bfu_hi(v.y);
            acc[4] += bfu_lo(v.z); acc[5] += bfu_hi(v.z);
            acc[6] += bfu_lo(v.w); acc[7] += bfu_hi(v.w);
        }
    }
#pragma unroll
    for (int j = 0; j < 8; j++) {
        acc[j] += __shfl_xor(acc[j], 16);
        acc[j] += __shfl_xor(acc[j], 32);
    }
    if (g == 0) {
        float inv = (deg > 0) ? 1.0f / (float)deg : 0.0f;
        uint4 o;
        o.x = (unsigned)f2bf(acc[0] * inv) | ((unsigned)f2bf(acc[1] * inv) << 16);
        o.y = (unsigned)f2bf(acc[2] * inv) | ((unsigned)f2bf(acc[3] * inv) << 16);
        o.z = (unsigned)f2bf(acc[4] * inv) | ((unsigned)f2bf(acc[5] * inv) << 16);
        o.w = (unsigned)f2bf(acc[6] * inv) | ((unsigned)f2bf(acc[7] * inv) << 16);
        out4[(size_t)wid * 16 + c16] = o;
    }
}

// ---------------- MFMA GEMM + fused epilogue (LDS-staged W, 1 row-tile/wave) ---------------
// C[M,N] = [A0|A1](bf16) @ Wp + bias; sigmoid + row-L2 (+ log_softmax if FINAL).
// R4 post-mortem: 2 row-tiles/wave needed ~192 live VGPRs; compiler allocated 88 and spilled
// acc to scratch (WRITE_SIZE 50->261MB, 148us). Revert to 1 row-tile (R3's proven 108-VGPR
// footprint) and keep the LDS staging. __launch_bounds__(256,2) budgets <=256 VGPR (occupancy
// is LDS-capped at 2 blocks/CU regardless). Phases are hand-split with if-constexpr and
// LITERAL acc offsets (acc[nt] / acc[8+nt]) so no accumulator index can go dynamic.
// W staged via global_load_lds (width 16) -> ds_read_b128 feeds MFMA with fine lgkmcnt.
// A-frags: row-major 16B loads (A[m=lane&15][k=quad*8+j]); K=256 resident in 32 VGPRs.
// C/D: row=quad*4+reg, col=lane&15 -> row reductions are shfl_xor width-16 within the quad.

template <int N, bool FINAL>
__global__ __launch_bounds__(256, 2) void gemm_mfma_kernel(
    const unsigned short* __restrict__ A0, const unsigned short* __restrict__ A1,
    const unsigned short* __restrict__ Wp, const float* __restrict__ bias,
    void* __restrict__ outp, int M) {
    const int NT = N / 16;   // total col tiles (8 or 16)
    const int NPH = NT / 8;  // 64KB stage phases (1 for N=128, 2 for N=256)
    __shared__ unsigned char sW[65536];
    int tid = threadIdx.x, wave = tid >> 6, lane = tid & 63;
    int quad = lane >> 4, col = lane & 15;
    int m_base = blockIdx.x * 64 + wave * 16;
    int row = m_base + col;
    int row_ld = row < M ? row : M - 1;

    // stage phase 0: each wave copies 16KB (16 x 1KB wave-instructions, async)
    {
        const char* gs = (const char*)Wp + wave * 16384;
        char* ld = (char*)sW + wave * 16384;  // wave-uniform LDS base (+lane*16 implicit)
#pragma unroll
        for (int j = 0; j < 16; j++) gload_lds16(gs + j * 1024 + lane * 16, ld + j * 1024);
    }

    // all 8 K-step A-frags (ks 0..3 from A0, 4..7 from A1)
    bf16x8 a[8];
    const uint4* a0p = (const uint4*)(A0 + (size_t)row_ld * 128 + quad * 8);
    const uint4* a1p = (const uint4*)(A1 + (size_t)row_ld * 128 + quad * 8);
#pragma unroll
    for (int ks = 0; ks < 4; ks++) { U16 u; u.u = a0p[ks * 4]; a[ks] = u.v; }
#pragma unroll
    for (int ks = 0; ks < 4; ks++) { U16 u; u.u = a1p[ks * 4]; a[4 + ks] = u.v; }

    f32x4 acc[NT];
#pragma unroll
    for (int nt = 0; nt < NT; nt++) acc[nt] = (f32x4){0.f, 0.f, 0.f, 0.f};

    // phase 0 compute (barrier drains vmcnt -> staged buffer ready)
    __syncthreads();
#pragma unroll
    for (int ks = 0; ks < 8; ks++) {
#pragma unroll
        for (int nt = 0; nt < 8; nt++) {
            U16 u; u.u = *(const uint4*)(sW + (nt * 8 + ks) * 1024 + lane * 16);
            acc[nt] = __builtin_amdgcn_mfma_f32_16x16x32_bf16(a[ks], u.v, acc[nt], 0, 0, 0);
        }
    }

    if constexpr (NPH == 2) {  // N=256: stage + compute second 64KB of W
        __syncthreads();       // all waves done reading phase-0 sW
        {
            const char* gs = (const char*)Wp + 65536 + wave * 16384;
            char* ld = (char*)sW + wave * 16384;
#pragma unroll
            for (int j = 0; j < 16; j++) gload_lds16(gs + j * 1024 + lane * 16, ld + j * 1024);
        }
        __syncthreads();  // drain vmcnt -> phase-1 buffer ready
#pragma unroll
        for (int ks = 0; ks < 8; ks++) {
#pragma unroll
            for (int nt = 0; nt < 8; nt++) {
                U16 u; u.u = *(const uint4*)(sW + (nt * 8 + ks) * 1024 + lane * 16);
                acc[8 + nt] = __builtin_amdgcn_mfma_f32_16x16x32_bf16(a[ks], u.v, acc[8 + nt], 0, 0, 0);
            }
        }
    }

    // epilogue: bias + sigmoid + row L2-norm
    float ssq[4] = {0.f, 0.f, 0.f, 0.f};
#pragma unroll
    for (int nt = 0; nt < NT; nt++) {
        float bv = bias[nt * 16 + col];
#pragma unroll
        for (int r = 0; r < 4; r++) {
            float z = acc[nt][r] + bv;
            float s = 1.0f / (1.0f + __expf(-z));
            acc[nt][r] = s;
            ssq[r] += s * s;
        }
    }
#pragma unroll
    for (int r = 0; r < 4; r++) {
#pragma unroll
        for (int off = 1; off < 16; off <<= 1) ssq[r] += __shfl_xor(ssq[r], off, 16);
        float sc = 1.0f / fmaxf(sqrtf(ssq[r]), 1e-12f);
#pragma unroll
        for (int nt = 0; nt < NT; nt++) acc[nt][r] *= sc;
    }

    if (FINAL) {  // log_softmax; values in (0,1] post sigmoid+L2norm -> exp-sum stable
                  // without max subtraction (validated R3: absmax unchanged).
#pragma unroll
        for (int r = 0; r < 4; r++) {
            float se = 0.f;
#pragma unroll
            for (int nt = 0; nt < NT; nt++) se += __expf(acc[nt][r]);
#pragma unroll
            for (int off = 1; off < 16; off <<= 1) se += __shfl_xor(se, off, 16);
            float lse = __logf(se);
#pragma unroll
            for (int nt = 0; nt < NT; nt++) acc[nt][r] -= lse;
        }
        float* op = (float*)outp;
#pragma unroll
        for (int r = 0; r < 4; r++) {
            int m = m_base + quad * 4 + r;
            if (m < M) {
#pragma unroll
                for (int nt = 0; nt < NT; nt++) op[(size_t)m * N + nt * 16 + col] = acc[nt][r];
            }
        }
    } else {  // bf16 out (feeds aggregation 2 + GEMM2 A-operand)
        unsigned short* op = (unsigned short*)outp;
#pragma unroll
        for (int r = 0; r < 4; r++) {
            int m = m_base + quad * 4 + r;
            if (m < M) {
#pragma unroll
                for (int nt = 0; nt < NT; nt++)
                    op[(size_t)m * N + nt * 16 + col] = f2bf(acc[nt][r]);
            }
        }
    }
}

// ---------------- launcher ----------------

extern "C" void kernel_launch(void* const* d_in, const int* in_sizes, int n_in,
                              void* d_out, int out_size, void* d_ws, size_t ws_size,
                              hipStream_t stream) {
    const float* x   = (const float*)d_in[0];
    const int*   ei  = (const int*)d_in[1];
    const float* W1l = (const float*)d_in[2];
    const float* W1r = (const float*)d_in[3];
    const float* b1  = (const float*)d_in[4];
    const float* W2l = (const float*)d_in[5];
    const float* W2r = (const float*)d_in[6];
    const float* b2  = (const float*)d_in[7];
    float* out = (float*)d_out;

    const int* src = ei;
    const int* dst = ei + NE;

    char* ws = (char*)d_ws;
    size_t off = 0;
    auto alloc = [&](size_t bytes) -> void* {
        void* p = ws + off;
        off += (bytes + 255) / 256 * 256;
        return p;
    };
    int* rowptr     = (int*)alloc((size_t)(NN + 1) * 4);
    int* col        = (int*)alloc((size_t)NE * 4);
    int* bcnt       = (int*)alloc((size_t)NB * 4);
    unsigned* ebuf  = (unsigned*)alloc((size_t)NB * CAP * 4);  // 4.8MB
    unsigned short* x_bf   = (unsigned short*)alloc((size_t)NN * 128 * 2);
    unsigned short* agg_bf = (unsigned short*)alloc((size_t)NN * 128 * 2);
    unsigned short* h1_bf  = (unsigned short*)alloc((size_t)NN * 128 * 2);
    unsigned short* W1p    = (unsigned short*)alloc((size_t)8 * 8 * 64 * 8 * 2);    // 64KB
    unsigned short* W2p    = (unsigned short*)alloc((size_t)16 * 8 * 64 * 8 * 2);   // 128KB

    // CSR build (graph identical for both layers — build once)
    hipMemsetAsync(bcnt, 0, (size_t)NB * 4, stream);
    binscatter_kernel<<<(NE + 8191) / 8192, 512, 0, stream>>>(src, dst, bcnt, ebuf);
    csr_kernel<<<NB, 256, 0, stream>>>(bcnt, ebuf, rowptr, col);

    // prep: cast x to bf16 + pack both weight sets (fused, one launch)
    castpack_kernel<<<CAST_BLK + 48, 256, 0, stream>>>(x, x_bf, W1l, W1r, W1p, W2l, W2r, W2p);

    // layer 1
    aggregate_bf_kernel<<<(NN + 3) / 4, 256, 0, stream>>>(rowptr, col, (const uint4*)x_bf,
                                                          (uint4*)agg_bf);
    gemm_mfma_kernel<128, false><<<(NN + 63) / 64, 256, 0, stream>>>(agg_bf, x_bf, W1p, b1,
                                                                     h1_bf, NN);
    // layer 2
    aggregate_bf_kernel<<<(NN + 3) / 4, 256, 0, stream>>>(rowptr, col, (const uint4*)h1_bf,
                                                          (uint4*)agg_bf);
    gemm_mfma_kernel<256, true><<<(NN + 63) / 64, 256, 0, stream>>>(agg_bf, h1_bf, W2p, b2,
                                                                    out, NN);
}